// Round 4
// baseline (507.915 us; speedup 1.0000x reference)
//
#include <hip/hip_runtime.h>

#define NBATCH 4
#define NPTS   16384
#define NQ     4096
#define NCH    64
#define K      32
#define CHOUT  67   // 3 + NCH

typedef float v2f __attribute__((ext_vector_type(2)));
typedef float v4f __attribute__((ext_vector_type(4)));
typedef int   v4i __attribute__((ext_vector_type(4)));

// Packed fp32 ops via asm: exact rn rounding, no contraction possible.
__device__ __forceinline__ v2f pk_add(v2f a, v2f b) {
    v2f d; asm("v_pk_add_f32 %0, %1, %2" : "=v"(d) : "v"(a), "v"(b)); return d;
}
__device__ __forceinline__ v2f pk_mul(v2f a, v2f b) {
    v2f d; asm("v_pk_mul_f32 %0, %1, %2" : "=v"(d) : "v"(a), "v"(b)); return d;
}
// Whole-wave shift lane i -> i+1 (DPP wave_shr:1, ctrl 0x138). Lane 0 keeps old.
__device__ __forceinline__ int dpp_shr1(int v) {
    return __builtin_amdgcn_update_dpp(v, v, 0x138, 0xf, 0xf, false);
}
// Per-lane select on an arbitrary 64-bit lane mask held in SGPRs: m ? t : f.
__device__ __forceinline__ int sel_mask_i(unsigned long long m, int t, int f) {
    int d; asm("v_cndmask_b32 %0, %2, %1, %3" : "=v"(d) : "v"(t), "v"(f), "s"(m));
    return d;
}

// ---------------------------------------------------------------------------
// Kernel 1: brute-force exact top-32 KNN + centered-xyz channels.
// block=256 (4 waves), QPW=4 queries/wave (4 independent insert chains for
// latency hiding), grid 1024. SoA LDS tiles, packed fp32 distances (exact:
// rn mul/add, sign of diff irrelevant after squaring). Top-32 list lives in
// lanes 0..31 sorted by (dist,idx); lanes 32..63 hold -inf sentinels.
// Inserts are SELF-GUARDING (ballot(ld>dn)==0 -> no-op), so the filter
// threshold T is refreshed only once per 128-candidate iteration (off the
// serial chain) and popped candidates need no recheck. Candidates popped in
// ascending point index -> exact jax.lax.top_k tie semantics.
// ---------------------------------------------------------------------------
constexpr int TILE = 2048;
constexpr int QPW  = 4;
constexpr int QPB  = 16;

__global__ __launch_bounds__(256) void knn_kernel(
    const float* __restrict__ xyz,
    const float* __restrict__ new_xyz,
    int*   __restrict__ out_idx,
    float* __restrict__ out)
{
    __shared__ float sx[TILE], sy[TILE], sz[TILE];   // 24 KB SoA

    const int tid  = threadIdx.x;
    const int lane = tid & 63;
    const int wave = tid >> 6;
    const int b    = blockIdx.x >> 8;                  // 256 blocks per batch
    const int q0   = (blockIdx.x & 255) * QPB + wave * QPW;

    const float* xb = xyz + (size_t)b * NPTS * 3;

    // Negated query coords (wave-uniform -> SGPR) + packed broadcasts.
    float nqx[QPW], nqy[QPW], nqz[QPW];
    v2f nqx2[QPW], nqy2[QPW], nqz2[QPW];
#pragma unroll
    for (int j = 0; j < QPW; ++j) {
        const int base = ((b * NQ) + q0 + j) * 3;
        nqx[j] = __int_as_float(__builtin_amdgcn_readfirstlane(__float_as_int(-new_xyz[base + 0])));
        nqy[j] = __int_as_float(__builtin_amdgcn_readfirstlane(__float_as_int(-new_xyz[base + 1])));
        nqz[j] = __int_as_float(__builtin_amdgcn_readfirstlane(__float_as_int(-new_xyz[base + 2])));
        nqx2[j] = (v2f){nqx[j], nqx[j]};
        nqy2[j] = (v2f){nqy[j], nqy[j]};
        nqz2[j] = (v2f){nqz[j], nqz[j]};
    }

    float ld[QPW]; int li[QPW]; float T[QPW];
    const float INF  = __int_as_float(0x7f800000);
    const float NINF = __int_as_float(0xff800000);
#pragma unroll
    for (int j = 0; j < QPW; ++j) {
        ld[j] = (lane < K) ? INF : NINF;   // -inf sentinel: lanes 32+ never ballot-pass
        li[j] = 0;
        T[j]  = INF;
    }

    for (int t0 = 0; t0 < NPTS; t0 += TILE) {
        __syncthreads();
        for (int i = tid; i < TILE; i += 256) {        // AoS global -> SoA LDS
            const float* s = xb + (size_t)(t0 + i) * 3;
            sx[i] = s[0]; sy[i] = s[1]; sz[i] = s[2];
        }
        __syncthreads();

        for (int ii = 0; ii < TILE / 2; ii += 64) {
            const int i = ii + lane;                   // this lane's point pair
            const v2f px2 = *(const v2f*)(sx + 2 * i);
            const v2f py2 = *(const v2f*)(sy + 2 * i);
            const v2f pz2 = *(const v2f*)(sz + 2 * i);
            const int ibase = t0 + 2 * ii;             // wave-uniform
#pragma unroll
            for (int j = 0; j < QPW; ++j) {
                const v2f dx = pk_add(px2, nqx2[j]);
                const v2f dy = pk_add(py2, nqy2[j]);
                const v2f dz = pk_add(pz2, nqz2[j]);
                const v2f d2 = pk_add(pk_add(pk_mul(dx, dx), pk_mul(dy, dy)),
                                      pk_mul(dz, dz));
                unsigned long long m0 = __ballot(d2.x < T[j]);
                unsigned long long m1 = __ballot(d2.y < T[j]);
                while (m0 | m1) {
                    const int c0 = m0 ? (int)__builtin_ctzll(m0) : 64;
                    const int c1 = m1 ? (int)__builtin_ctzll(m1) : 64;
                    const bool lo = c0 <= c1;          // ascending candidate index
                    const int c = lo ? c0 : c1;
                    if (lo) m0 &= m0 - 1; else m1 &= m1 - 1;
                    const int b0 = __builtin_amdgcn_readlane(__float_as_int(d2.x), c);
                    const int b1 = __builtin_amdgcn_readlane(__float_as_int(d2.y), c);
                    const float dn = __int_as_float(lo ? b0 : b1);
                    const int cand = ibase + 2 * c + (lo ? 0 : 1);
                    // Self-guarding sorted insert (no-op if dn >= current max).
                    const unsigned long long sh = __ballot(ld[j] > dn);
                    const int p = sh ? (int)__builtin_ctzll(sh) : 64;
                    const int sld = dpp_shr1(__float_as_int(ld[j]));
                    const int sli = dpp_shr1(li[j]);
                    const int nld = sel_mask_i(sh, sld, __float_as_int(ld[j]));
                    const int nli = sel_mask_i(sh, sli, li[j]);
                    ld[j] = __int_as_float((lane == p) ? __float_as_int(dn) : nld);
                    li[j] = (lane == p) ? cand : nli;
                }
                T[j] = __int_as_float(__builtin_amdgcn_readlane(__float_as_int(ld[j]), 31));
            }
        }
    }

    // Epilogue: write idx + centered xyz channels (0..2).
#pragma unroll
    for (int j = 0; j < QPW; ++j) {
        if (lane < K) {
            const int q   = q0 + j;
            const int idx = li[j];
            out_idx[((size_t)(b * NQ) + q) * K + lane] = idx;
            const float px = xb[idx * 3 + 0];
            const float py = xb[idx * 3 + 1];
            const float pz = xb[idx * 3 + 2];
            const size_t plane = (size_t)NQ * K;
            const size_t o = (((size_t)b * CHOUT + 0) * NQ + q) * K + lane;
            out[o]             = __fadd_rn(px, nqx[j]);   // == px - qx, exact
            out[o + plane]     = __fadd_rn(py, nqy[j]);
            out[o + 2 * plane] = __fadd_rn(pz, nqz[j]);
        }
    }
}

// ---------------------------------------------------------------------------
// Kernel 2: feature gather, channels 3..66.
// grid = B x NCH x 2 halves = 512 blocks, block = 1024 -> 2 blocks/CU
// (64 KB LDS each), 32 waves/CU. Each block stages one full feature row and
// gathers half the (q,k) entries: int4 idx loads + 4 LDS reads + nt float4
// coalesced stores (streaming 134 MB write, keep L2 for features/idx).
// ---------------------------------------------------------------------------
__global__ __launch_bounds__(1024) void gather_kernel(
    const float* __restrict__ features,
    const int*   __restrict__ idx,
    float* __restrict__ out)
{
    __shared__ __align__(16) float row[NPTS];   // 64 KB

    const int tid  = threadIdx.x;
    const int half = blockIdx.x & 1;
    const int c    = (blockIdx.x >> 1) & 63;
    const int b    = blockIdx.x >> 7;

    const v4f* src = (const v4f*)(features + ((size_t)(b * NCH + c)) * NPTS);
    for (int k2 = tid; k2 < NPTS / 4; k2 += 1024) ((v4f*)row)[k2] = src[k2];
    __syncthreads();

    const size_t hofs = (size_t)half * (NQ * K / 2);
    const v4i* gi = (const v4i*)(idx + (size_t)b * NQ * K + hofs);
    v4f* dst = (v4f*)(out + ((size_t)(b * CHOUT + 3 + c)) * NQ * K + hofs);
#pragma unroll 4
    for (int p = tid; p < NQ * K / 8; p += 1024) {
        const v4i ii = gi[p];
        v4f o;
        o.x = row[ii.x]; o.y = row[ii.y]; o.z = row[ii.z]; o.w = row[ii.w];
        __builtin_nontemporal_store(o, dst + p);
    }
}

extern "C" void kernel_launch(void* const* d_in, const int* in_sizes, int n_in,
                              void* d_out, int out_size, void* d_ws, size_t ws_size,
                              hipStream_t stream) {
    const float* xyz      = (const float*)d_in[0];
    const float* new_xyz  = (const float*)d_in[1];
    const float* features = (const float*)d_in[2];
    float* out    = (float*)d_out;
    int*   ws_idx = (int*)d_ws;   // 4*4096*32*4 = 2 MB scratch

    knn_kernel<<<dim3(NBATCH * (NQ / QPB)), dim3(256), 0, stream>>>(xyz, new_xyz, ws_idx, out);
    gather_kernel<<<dim3(NBATCH * NCH * 2), dim3(1024), 0, stream>>>(features, ws_idx, out);
}

// Round 5
// 336.162 us; speedup vs baseline: 1.5109x; 1.5109x over previous
//
#include <hip/hip_runtime.h>

#define NBATCH 4
#define NPTS   16384
#define NQ     4096
#define NCH    64
#define K      32
#define CHOUT  67   // 3 + NCH

typedef float v2f __attribute__((ext_vector_type(2)));
typedef float v4f __attribute__((ext_vector_type(4)));
typedef int   v4i __attribute__((ext_vector_type(4)));

// Packed fp32 ops via asm: exact rn rounding, no contraction possible.
__device__ __forceinline__ v2f pk_add(v2f a, v2f b) {
    v2f d; asm("v_pk_add_f32 %0, %1, %2" : "=v"(d) : "v"(a), "v"(b)); return d;
}
__device__ __forceinline__ v2f pk_mul(v2f a, v2f b) {
    v2f d; asm("v_pk_mul_f32 %0, %1, %2" : "=v"(d) : "v"(a), "v"(b)); return d;
}
// Whole-wave shift lane i -> i+1 (DPP wave_shr:1, ctrl 0x138). Lane 0 keeps old.
__device__ __forceinline__ int dpp_shr1(int v) {
    return __builtin_amdgcn_update_dpp(v, v, 0x138, 0xf, 0xf, false);
}
// Per-lane select on an arbitrary 64-bit lane mask held in SGPRs: m ? t : f.
__device__ __forceinline__ int sel_mask_i(unsigned long long m, int t, int f) {
    int d; asm("v_cndmask_b32 %0, %2, %1, %3" : "=v"(d) : "v"(t), "v"(f), "s"(m));
    return d;
}

// ---------------------------------------------------------------------------
// Kernel 1: exact top-32 KNN + centered-xyz channels, filter-then-select.
//   Pass 1: full scan, per-lane running min per query (pure VALU, no
//           cross-lane serialization).
//   T':     exact 32nd-smallest of the 64 lane minima via radix bit-descent
//           on float bits (uint-ordered for nonneg floats). T' is a provable
//           upper bound on the true 32nd distance, so pass 2 is exact even
//           if T' is loose.
//   Pass 2: rescan; ballot(d <= T') per 128 candidates (usually zero ->
//           cheap skip); survivors (~44/query) pop in ascending point index
//           through the sorted distributed top-32 insert (self-guarding,
//           strict-greater shift -> exact jax.lax.top_k tie semantics).
// block=256 (4 waves), QPW=4 queries/wave, grid 1024, 24 KB LDS SoA tiles.
// ---------------------------------------------------------------------------
constexpr int TILE = 2048;
constexpr int QPW  = 4;
constexpr int QPB  = 16;

__global__ __launch_bounds__(256) void knn_kernel(
    const float* __restrict__ xyz,
    const float* __restrict__ new_xyz,
    int*   __restrict__ out_idx,
    float* __restrict__ out)
{
    __shared__ float sx[TILE], sy[TILE], sz[TILE];   // 24 KB SoA

    const int tid  = threadIdx.x;
    const int lane = tid & 63;
    const int wave = tid >> 6;
    const int b    = blockIdx.x >> 8;                  // 256 blocks per batch
    const int q0   = (blockIdx.x & 255) * QPB + wave * QPW;

    const float* xb = xyz + (size_t)b * NPTS * 3;

    // Negated query coords (wave-uniform -> SGPR) + packed VGPR broadcasts.
    float nqx[QPW], nqy[QPW], nqz[QPW];
    v2f nqx2[QPW], nqy2[QPW], nqz2[QPW];
#pragma unroll
    for (int j = 0; j < QPW; ++j) {
        const int base = ((b * NQ) + q0 + j) * 3;
        nqx[j] = __int_as_float(__builtin_amdgcn_readfirstlane(__float_as_int(-new_xyz[base + 0])));
        nqy[j] = __int_as_float(__builtin_amdgcn_readfirstlane(__float_as_int(-new_xyz[base + 1])));
        nqz[j] = __int_as_float(__builtin_amdgcn_readfirstlane(__float_as_int(-new_xyz[base + 2])));
        nqx2[j] = (v2f){nqx[j], nqx[j]};
        nqy2[j] = (v2f){nqy[j], nqy[j]};
        nqz2[j] = (v2f){nqz[j], nqz[j]};
    }

    const float INF  = __int_as_float(0x7f800000);
    const float NINF = __int_as_float(0xff800000);

    // ---------------- Pass 1: per-lane running minima ----------------
    float vmA[QPW], vmB[QPW];
#pragma unroll
    for (int j = 0; j < QPW; ++j) { vmA[j] = INF; vmB[j] = INF; }

    for (int t0 = 0; t0 < NPTS; t0 += TILE) {
        __syncthreads();
        for (int i = tid; i < TILE; i += 256) {        // AoS global -> SoA LDS
            const float* s = xb + (size_t)(t0 + i) * 3;
            sx[i] = s[0]; sy[i] = s[1]; sz[i] = s[2];
        }
        __syncthreads();

        for (int ii = 0; ii < TILE / 2; ii += 64) {
            const int i = ii + lane;
            const v2f px2 = *(const v2f*)(sx + 2 * i);
            const v2f py2 = *(const v2f*)(sy + 2 * i);
            const v2f pz2 = *(const v2f*)(sz + 2 * i);
#pragma unroll
            for (int j = 0; j < QPW; ++j) {
                const v2f dx = pk_add(px2, nqx2[j]);
                const v2f dy = pk_add(py2, nqy2[j]);
                const v2f dz = pk_add(pz2, nqz2[j]);
                const v2f d2 = pk_add(pk_add(pk_mul(dx, dx), pk_mul(dy, dy)),
                                      pk_mul(dz, dz));
                vmA[j] = fminf(vmA[j], d2.x);
                vmB[j] = fminf(vmB[j], d2.y);
            }
        }
    }

    // ---------------- T' = exact 32nd smallest of 64 lane minima -----
    float Tf[QPW];
#pragma unroll
    for (int j = 0; j < QPW; ++j) {
        const unsigned u = __float_as_uint(fminf(vmA[j], vmB[j]));
        unsigned t = 0x7fffffffu;                       // > all finite bits
        for (int bb = 30; bb >= 0; --bb) {              // uniform radix descent
            const unsigned tt = t ^ (1u << bb);
            const int cnt = __popcll(__ballot(u <= tt));
            if (cnt >= 32) t = tt;                      // s_cselect, branchless
        }
        Tf[j] = __uint_as_float(t);
    }

    // ---------------- Pass 2: filtered exact selection ---------------
    float ld[QPW]; int li[QPW];
#pragma unroll
    for (int j = 0; j < QPW; ++j) {
        ld[j] = (lane < K) ? INF : NINF;   // -inf sentinel: lanes 32+ never shift
        li[j] = 0;
    }

    for (int t0 = 0; t0 < NPTS; t0 += TILE) {
        __syncthreads();
        for (int i = tid; i < TILE; i += 256) {
            const float* s = xb + (size_t)(t0 + i) * 3;
            sx[i] = s[0]; sy[i] = s[1]; sz[i] = s[2];
        }
        __syncthreads();

        for (int ii = 0; ii < TILE / 2; ii += 64) {
            const int i = ii + lane;
            const v2f px2 = *(const v2f*)(sx + 2 * i);
            const v2f py2 = *(const v2f*)(sy + 2 * i);
            const v2f pz2 = *(const v2f*)(sz + 2 * i);
            const int ibase = t0 + 2 * ii;             // wave-uniform
#pragma unroll
            for (int j = 0; j < QPW; ++j) {
                const v2f dx = pk_add(px2, nqx2[j]);
                const v2f dy = pk_add(py2, nqy2[j]);
                const v2f dz = pk_add(pz2, nqz2[j]);
                const v2f d2 = pk_add(pk_add(pk_mul(dx, dx), pk_mul(dy, dy)),
                                      pk_mul(dz, dz));
                unsigned long long m0 = __ballot(d2.x <= Tf[j]);
                unsigned long long m1 = __ballot(d2.y <= Tf[j]);
                while (m0 | m1) {                       // ~44 total pops/query
                    const int c0 = m0 ? (int)__builtin_ctzll(m0) : 64;
                    const int c1 = m1 ? (int)__builtin_ctzll(m1) : 64;
                    const bool lo = c0 <= c1;           // ascending candidate index
                    const int c = lo ? c0 : c1;
                    if (lo) m0 &= m0 - 1; else m1 &= m1 - 1;
                    const int b0 = __builtin_amdgcn_readlane(__float_as_int(d2.x), c);
                    const int b1 = __builtin_amdgcn_readlane(__float_as_int(d2.y), c);
                    const float dn = __int_as_float(lo ? b0 : b1);
                    const int cand = ibase + 2 * c + (lo ? 0 : 1);
                    // Self-guarding sorted insert (no-op if dn >= current max).
                    const unsigned long long sh = __ballot(ld[j] > dn);
                    const int p = sh ? (int)__builtin_ctzll(sh) : 64;
                    const int sld = dpp_shr1(__float_as_int(ld[j]));
                    const int sli = dpp_shr1(li[j]);
                    const int nld = sel_mask_i(sh, sld, __float_as_int(ld[j]));
                    const int nli = sel_mask_i(sh, sli, li[j]);
                    ld[j] = __int_as_float((lane == p) ? __float_as_int(dn) : nld);
                    li[j] = (lane == p) ? cand : nli;
                }
            }
        }
    }

    // Epilogue: write idx + centered xyz channels (0..2).
#pragma unroll
    for (int j = 0; j < QPW; ++j) {
        if (lane < K) {
            const int q   = q0 + j;
            const int idx = li[j];
            out_idx[((size_t)(b * NQ) + q) * K + lane] = idx;
            const float px = xb[idx * 3 + 0];
            const float py = xb[idx * 3 + 1];
            const float pz = xb[idx * 3 + 2];
            const size_t plane = (size_t)NQ * K;
            const size_t o = (((size_t)b * CHOUT + 0) * NQ + q) * K + lane;
            out[o]             = __fadd_rn(px, nqx[j]);   // == px - qx, exact
            out[o + plane]     = __fadd_rn(py, nqy[j]);
            out[o + 2 * plane] = __fadd_rn(pz, nqz[j]);
        }
    }
}

// ---------------------------------------------------------------------------
// Kernel 2: feature gather, channels 3..66.
// grid = B x NCH x 2 halves = 512 blocks (2 blocks/CU, full residency),
// block = 1024. Stage one feature row (64 KB LDS), then a 2-stage software
// pipeline: idx int4 prefetch overlaps the 4 random LDS reads + nt store.
// ---------------------------------------------------------------------------
__global__ __launch_bounds__(1024) void gather_kernel(
    const float* __restrict__ features,
    const int*   __restrict__ idx,
    float* __restrict__ out)
{
    __shared__ __align__(16) float row[NPTS];   // 64 KB

    const int tid  = threadIdx.x;
    const int half = blockIdx.x & 1;
    const int c    = (blockIdx.x >> 1) & 63;
    const int b    = blockIdx.x >> 7;

    const v4f* src = (const v4f*)(features + ((size_t)(b * NCH + c)) * NPTS);
    for (int k2 = tid; k2 < NPTS / 4; k2 += 1024) ((v4f*)row)[k2] = src[k2];
    __syncthreads();

    const size_t hofs = (size_t)half * (NQ * K / 2);
    const v4i* gi = (const v4i*)(idx + (size_t)b * NQ * K + hofs);
    v4f* dst = (v4f*)(out + ((size_t)(b * CHOUT + 3 + c)) * NQ * K + hofs);

    v4i cur = gi[tid];
#pragma unroll
    for (int it = 0; it < 16; ++it) {                  // NQ*K/8/1024 = 16
        v4i nxt;
        if (it < 15) nxt = gi[tid + (it + 1) * 1024];
        v4f o;
        o.x = row[cur.x]; o.y = row[cur.y]; o.z = row[cur.z]; o.w = row[cur.w];
        __builtin_nontemporal_store(o, dst + tid + it * 1024);
        cur = nxt;
    }
}

extern "C" void kernel_launch(void* const* d_in, const int* in_sizes, int n_in,
                              void* d_out, int out_size, void* d_ws, size_t ws_size,
                              hipStream_t stream) {
    const float* xyz      = (const float*)d_in[0];
    const float* new_xyz  = (const float*)d_in[1];
    const float* features = (const float*)d_in[2];
    float* out    = (float*)d_out;
    int*   ws_idx = (int*)d_ws;   // 4*4096*32*4 = 2 MB scratch

    knn_kernel<<<dim3(NBATCH * (NQ / QPB)), dim3(256), 0, stream>>>(xyz, new_xyz, ws_idx, out);
    gather_kernel<<<dim3(NBATCH * NCH * 2), dim3(1024), 0, stream>>>(features, ws_idx, out);
}

// Round 6
// 305.542 us; speedup vs baseline: 1.6623x; 1.1002x over previous
//
#include <hip/hip_runtime.h>

#define NBATCH 4
#define NPTS   16384
#define NQ     4096
#define NCH    64
#define K      32
#define CHOUT  67   // 3 + NCH

typedef float v2f __attribute__((ext_vector_type(2)));
typedef float v4f __attribute__((ext_vector_type(4)));
typedef int   v4i __attribute__((ext_vector_type(4)));

// Packed fp32 ops via asm: exact rn rounding, no contraction possible.
__device__ __forceinline__ v2f pk_add(v2f a, v2f b) {
    v2f d; asm("v_pk_add_f32 %0, %1, %2" : "=v"(d) : "v"(a), "v"(b)); return d;
}
__device__ __forceinline__ v2f pk_mul(v2f a, v2f b) {
    v2f d; asm("v_pk_mul_f32 %0, %1, %2" : "=v"(d) : "v"(a), "v"(b)); return d;
}
// Whole-wave shift lane i -> i+1 (DPP wave_shr:1, ctrl 0x138). Lane 0 keeps old.
__device__ __forceinline__ int dpp_shr1(int v) {
    return __builtin_amdgcn_update_dpp(v, v, 0x138, 0xf, 0xf, false);
}
// Per-lane select on an arbitrary 64-bit lane mask held in SGPRs: m ? t : f.
__device__ __forceinline__ int sel_mask_i(unsigned long long m, int t, int f) {
    int d; asm("v_cndmask_b32 %0, %2, %1, %3" : "=v"(d) : "v"(t), "v"(f), "s"(m));
    return d;
}

// ---------------------------------------------------------------------------
// Kernel 1: exact top-32 KNN + centered-xyz channels, filter-then-select.
//   Pass 1: full scan, per-lane running min per query (pure VALU).
//   T':     exact 32nd-smallest of the 64 lane minima via radix bit-descent
//           (provable upper bound on true 32nd distance -> pass 2 exact).
//   Pass 2: rescan; ballot(d <= T'); survivors (~44/query) pop in ascending
//           point index through the sorted distributed top-32 insert.
// R6: QPW=2, QPB=8, TILE=1024 (12 KB LDS), grid 2048 -> 8 blocks/CU,
// 32 waves/CU (100% occupancy cap) to hide the LDS->VALU chains.
// ---------------------------------------------------------------------------
constexpr int TILE = 1024;
constexpr int QPW  = 2;
constexpr int QPB  = 8;

__global__ __launch_bounds__(256) void knn_kernel(
    const float* __restrict__ xyz,
    const float* __restrict__ new_xyz,
    int*   __restrict__ out_idx,
    float* __restrict__ out)
{
    __shared__ float sx[TILE], sy[TILE], sz[TILE];   // 12 KB SoA

    const int tid  = threadIdx.x;
    const int lane = tid & 63;
    const int wave = tid >> 6;
    const int b    = blockIdx.x >> 9;                  // 512 blocks per batch
    const int q0   = (blockIdx.x & 511) * QPB + wave * QPW;

    const float* xb = xyz + (size_t)b * NPTS * 3;

    // Negated query coords (wave-uniform -> SGPR) + packed VGPR broadcasts.
    float nqx[QPW], nqy[QPW], nqz[QPW];
    v2f nqx2[QPW], nqy2[QPW], nqz2[QPW];
#pragma unroll
    for (int j = 0; j < QPW; ++j) {
        const int base = ((b * NQ) + q0 + j) * 3;
        nqx[j] = __int_as_float(__builtin_amdgcn_readfirstlane(__float_as_int(-new_xyz[base + 0])));
        nqy[j] = __int_as_float(__builtin_amdgcn_readfirstlane(__float_as_int(-new_xyz[base + 1])));
        nqz[j] = __int_as_float(__builtin_amdgcn_readfirstlane(__float_as_int(-new_xyz[base + 2])));
        nqx2[j] = (v2f){nqx[j], nqx[j]};
        nqy2[j] = (v2f){nqy[j], nqy[j]};
        nqz2[j] = (v2f){nqz[j], nqz[j]};
    }

    const float INF  = __int_as_float(0x7f800000);
    const float NINF = __int_as_float(0xff800000);

    // ---------------- Pass 1: per-lane running minima ----------------
    float vmA[QPW], vmB[QPW];
#pragma unroll
    for (int j = 0; j < QPW; ++j) { vmA[j] = INF; vmB[j] = INF; }

    for (int t0 = 0; t0 < NPTS; t0 += TILE) {
        __syncthreads();
        for (int i = tid; i < TILE; i += 256) {        // AoS global -> SoA LDS
            const float* s = xb + (size_t)(t0 + i) * 3;
            sx[i] = s[0]; sy[i] = s[1]; sz[i] = s[2];
        }
        __syncthreads();

#pragma unroll 2
        for (int ii = 0; ii < TILE / 2; ii += 64) {
            const int i = ii + lane;
            const v2f px2 = *(const v2f*)(sx + 2 * i);
            const v2f py2 = *(const v2f*)(sy + 2 * i);
            const v2f pz2 = *(const v2f*)(sz + 2 * i);
#pragma unroll
            for (int j = 0; j < QPW; ++j) {
                const v2f dx = pk_add(px2, nqx2[j]);
                const v2f dy = pk_add(py2, nqy2[j]);
                const v2f dz = pk_add(pz2, nqz2[j]);
                const v2f d2 = pk_add(pk_add(pk_mul(dx, dx), pk_mul(dy, dy)),
                                      pk_mul(dz, dz));
                vmA[j] = fminf(vmA[j], d2.x);
                vmB[j] = fminf(vmB[j], d2.y);
            }
        }
    }

    // ---------------- T' = exact 32nd smallest of 64 lane minima -----
    float Tf[QPW];
#pragma unroll
    for (int j = 0; j < QPW; ++j) {
        const unsigned u = __float_as_uint(fminf(vmA[j], vmB[j]));
        unsigned t = 0x7fffffffu;                       // > all finite bits
        for (int bb = 30; bb >= 0; --bb) {              // uniform radix descent
            const unsigned tt = t ^ (1u << bb);
            const int cnt = __popcll(__ballot(u <= tt));
            if (cnt >= 32) t = tt;                      // s_cselect, branchless
        }
        Tf[j] = __uint_as_float(t);
    }

    // ---------------- Pass 2: filtered exact selection ---------------
    float ld[QPW]; int li[QPW];
#pragma unroll
    for (int j = 0; j < QPW; ++j) {
        ld[j] = (lane < K) ? INF : NINF;   // -inf sentinel: lanes 32+ never shift
        li[j] = 0;
    }

    for (int t0 = 0; t0 < NPTS; t0 += TILE) {
        __syncthreads();
        for (int i = tid; i < TILE; i += 256) {
            const float* s = xb + (size_t)(t0 + i) * 3;
            sx[i] = s[0]; sy[i] = s[1]; sz[i] = s[2];
        }
        __syncthreads();

#pragma unroll 2
        for (int ii = 0; ii < TILE / 2; ii += 64) {
            const int i = ii + lane;
            const v2f px2 = *(const v2f*)(sx + 2 * i);
            const v2f py2 = *(const v2f*)(sy + 2 * i);
            const v2f pz2 = *(const v2f*)(sz + 2 * i);
            const int ibase = t0 + 2 * ii;             // wave-uniform
#pragma unroll
            for (int j = 0; j < QPW; ++j) {
                const v2f dx = pk_add(px2, nqx2[j]);
                const v2f dy = pk_add(py2, nqy2[j]);
                const v2f dz = pk_add(pz2, nqz2[j]);
                const v2f d2 = pk_add(pk_add(pk_mul(dx, dx), pk_mul(dy, dy)),
                                      pk_mul(dz, dz));
                unsigned long long m0 = __ballot(d2.x <= Tf[j]);
                unsigned long long m1 = __ballot(d2.y <= Tf[j]);
                while (m0 | m1) {                       // ~44 total pops/query
                    const int c0 = m0 ? (int)__builtin_ctzll(m0) : 64;
                    const int c1 = m1 ? (int)__builtin_ctzll(m1) : 64;
                    const bool lo = c0 <= c1;           // ascending candidate index
                    const int c = lo ? c0 : c1;
                    if (lo) m0 &= m0 - 1; else m1 &= m1 - 1;
                    const int b0 = __builtin_amdgcn_readlane(__float_as_int(d2.x), c);
                    const int b1 = __builtin_amdgcn_readlane(__float_as_int(d2.y), c);
                    const float dn = __int_as_float(lo ? b0 : b1);
                    const int cand = ibase + 2 * c + (lo ? 0 : 1);
                    // Self-guarding sorted insert (no-op if dn >= current max).
                    const unsigned long long sh = __ballot(ld[j] > dn);
                    const int p = sh ? (int)__builtin_ctzll(sh) : 64;
                    const int sld = dpp_shr1(__float_as_int(ld[j]));
                    const int sli = dpp_shr1(li[j]);
                    const int nld = sel_mask_i(sh, sld, __float_as_int(ld[j]));
                    const int nli = sel_mask_i(sh, sli, li[j]);
                    ld[j] = __int_as_float((lane == p) ? __float_as_int(dn) : nld);
                    li[j] = (lane == p) ? cand : nli;
                }
            }
        }
    }

    // Epilogue: write idx + centered xyz channels (0..2).
#pragma unroll
    for (int j = 0; j < QPW; ++j) {
        if (lane < K) {
            const int q   = q0 + j;
            const int idx = li[j];
            out_idx[((size_t)(b * NQ) + q) * K + lane] = idx;
            const float px = xb[idx * 3 + 0];
            const float py = xb[idx * 3 + 1];
            const float pz = xb[idx * 3 + 2];
            const size_t plane = (size_t)NQ * K;
            const size_t o = (((size_t)b * CHOUT + 0) * NQ + q) * K + lane;
            out[o]             = __fadd_rn(px, nqx[j]);   // == px - qx, exact
            out[o + plane]     = __fadd_rn(py, nqy[j]);
            out[o + 2 * plane] = __fadd_rn(pz, nqz[j]);
        }
    }
}

// ---------------------------------------------------------------------------
// Kernel 2: feature gather, channels 3..66.
// grid = B x NCH x 2 halves = 512 blocks (2 blocks/CU), block = 1024.
// Stage one feature row (64 KB LDS), 2-stage idx prefetch pipeline, plain
// (L2 write-back) stores this round — testing whether nt was throttling.
// ---------------------------------------------------------------------------
__global__ __launch_bounds__(1024) void gather_kernel(
    const float* __restrict__ features,
    const int*   __restrict__ idx,
    float* __restrict__ out)
{
    __shared__ __align__(16) float row[NPTS];   // 64 KB

    const int tid  = threadIdx.x;
    const int half = blockIdx.x & 1;
    const int c    = (blockIdx.x >> 1) & 63;
    const int b    = blockIdx.x >> 7;

    const v4f* src = (const v4f*)(features + ((size_t)(b * NCH + c)) * NPTS);
    for (int k2 = tid; k2 < NPTS / 4; k2 += 1024) ((v4f*)row)[k2] = src[k2];
    __syncthreads();

    const size_t hofs = (size_t)half * (NQ * K / 2);
    const v4i* gi = (const v4i*)(idx + (size_t)b * NQ * K + hofs);
    v4f* dst = (v4f*)(out + ((size_t)(b * CHOUT + 3 + c)) * NQ * K + hofs);

    v4i cur = gi[tid];
#pragma unroll
    for (int it = 0; it < 16; ++it) {                  // NQ*K/8/1024 = 16
        v4i nxt;
        if (it < 15) nxt = gi[tid + (it + 1) * 1024];
        v4f o;
        o.x = row[cur.x]; o.y = row[cur.y]; o.z = row[cur.z]; o.w = row[cur.w];
        dst[tid + it * 1024] = o;
        cur = nxt;
    }
}

extern "C" void kernel_launch(void* const* d_in, const int* in_sizes, int n_in,
                              void* d_out, int out_size, void* d_ws, size_t ws_size,
                              hipStream_t stream) {
    const float* xyz      = (const float*)d_in[0];
    const float* new_xyz  = (const float*)d_in[1];
    const float* features = (const float*)d_in[2];
    float* out    = (float*)d_out;
    int*   ws_idx = (int*)d_ws;   // 4*4096*32*4 = 2 MB scratch

    knn_kernel<<<dim3(NBATCH * (NQ / QPB)), dim3(256), 0, stream>>>(xyz, new_xyz, ws_idx, out);
    gather_kernel<<<dim3(NBATCH * NCH * 2), dim3(1024), 0, stream>>>(features, ws_idx, out);
}